// Round 6
// baseline (263.579 us; speedup 1.0000x reference)
//
#include <hip/hip_runtime.h>

// Instant-NGP multires hash encoding fwd. N=1M, L=16, F=2, T=2^19.
// R10 (from R9 @ 247.6us; k_main 107us proven, aux ~140us):
//  - Theory: aux cost is the scatter's 1M random 16B stores into 16MB
//    (partial 64B lines dirtied across non-coherent XCD L2 slices).
//  - Fix: scatter only the 4B perm (4MB region, L2-resident), then a
//    separate k_gather makes sorted xs with COALESCED writes (random x
//    reads hit L2: x is 12MB). k_main unchanged (R7/R9 form).

__constant__ float c_res[16] = {
    16.f, 18.f, 21.f, 24.f, 27.f, 32.f, 36.f, 42.f,
    48.f, 55.f, 64.f, 73.f, 84.f, 97.f, 111.f, 128.f
};

#define TMASK   0x7FFFFu
#define PRIME1  2654435761u
#define PRIME2  805459861u
#define NBUCKET 4096          // 16^3 cells
#define NB      256           // sort blocks (hist & scatter use SAME chunking)
#define NGRP    16            // grpsum rows; group = 16 consecutive blocks
#define CACHE_N 4467          // sum over levels of max corners — exact bound

__device__ __forceinline__ int bucket_of(float x0, float x1, float x2) {
    // x*16 is EXACT in fp32 (power-of-2 scale), so cell membership is exact.
    int c0 = (int)(x0 * 16.f); c0 = c0 < 0 ? 0 : (c0 > 15 ? 15 : c0);
    int c1 = (int)(x1 * 16.f); c1 = c1 < 0 ? 0 : (c1 > 15 ? 15 : c1);
    int c2 = (int)(x2 * 16.f); c2 = c2 < 0 ? 0 : (c2 > 15 ? 15 : c2);
    return (c0 << 8) | (c1 << 4) | c2;
}

// ---- aux 1: per-block LDS histogram -> cnt row + grpsum atomic merge ----
__global__ __launch_bounds__(1024)
void k_histA(const float* __restrict__ x, unsigned* __restrict__ cnt,
             unsigned* __restrict__ grpsum, int npts)
{
    __shared__ unsigned h[NBUCKET];
    for (int j = threadIdx.x; j < NBUCKET; j += 1024) h[j] = 0u;
    __syncthreads();
    int chunk = (npts + NB - 1) / NB;
    int begin = blockIdx.x * chunk;
    int end   = begin + chunk; if (end > npts) end = npts;
    for (int i = begin + threadIdx.x; i < end; i += 1024) {
        int b = bucket_of(x[3 * i], x[3 * i + 1], x[3 * i + 2]);
        atomicAdd(&h[b], 1u);              // LDS atomic — cheap
    }
    __syncthreads();
    unsigned* grow = grpsum + (size_t)(blockIdx.x >> 4) * NBUCKET;
    for (int j = threadIdx.x; j < NBUCKET; j += 1024) {
        unsigned v = h[j];
        cnt[(size_t)blockIdx.x * NBUCKET + j] = v;
        if (v) atomicAdd(&grow[j], v);     // ~700K atomics, 16-way avg
    }
}

// ---- aux 2: rebuild prefix info per block, then scatter perm (4B only) ----
// cursor(blk, j) = starts[j] + sum_{g < blk/16} grpsum[g][j]
//                + sum_{r in [blk&~15, blk)} cnt[r][j]
__global__ __launch_bounds__(1024)
void k_scatB(const float* __restrict__ x, const unsigned* __restrict__ cnt,
             const unsigned* __restrict__ grpsum, unsigned* __restrict__ starts,
             unsigned* __restrict__ perm, int npts)
{
    __shared__ unsigned cur[NBUCKET];
    __shared__ unsigned tmp[1024];
    const int t   = threadIdx.x;
    const int blk = blockIdx.x;
    const int myg = blk >> 4;
    const int r0  = blk & ~15;

    const uint4* gs4 = (const uint4*)grpsum;   // [NGRP][1024] uint4
    const uint4* ct4 = (const uint4*)cnt;      // [NB]  [1024] uint4
    uint4 tot = make_uint4(0u,0u,0u,0u), bas = make_uint4(0u,0u,0u,0u);
    #pragma unroll
    for (int g = 0; g < NGRP; ++g) {
        uint4 v = gs4[g * 1024 + t];
        tot.x += v.x; tot.y += v.y; tot.z += v.z; tot.w += v.w;
        if (g < myg) { bas.x += v.x; bas.y += v.y; bas.z += v.z; bas.w += v.w; }
    }
    for (int r = r0; r < blk; ++r) {
        uint4 v = ct4[r * 1024 + t];
        bas.x += v.x; bas.y += v.y; bas.z += v.z; bas.w += v.w;
    }
    // replicated exclusive scan of the 4096 column totals
    unsigned s = tot.x + tot.y + tot.z + tot.w;
    tmp[t] = s;
    __syncthreads();
    for (int off = 1; off < 1024; off <<= 1) {
        unsigned u = (t >= off) ? tmp[t - off] : 0u;
        __syncthreads();
        tmp[t] += u;
        __syncthreads();
    }
    unsigned excl = tmp[t] - s;
    unsigned s0 = excl, s1 = s0 + tot.x, s2 = s1 + tot.y, s3 = s2 + tot.z;
    cur[4*t+0] = s0 + bas.x;
    cur[4*t+1] = s1 + bas.y;
    cur[4*t+2] = s2 + bas.z;
    cur[4*t+3] = s3 + bas.w;
    if (blk == 0) {        // publish starts for k_main
        starts[4*t+0] = s0; starts[4*t+1] = s1;
        starts[4*t+2] = s2; starts[4*t+3] = s3;
        if (t == 1023) starts[NBUCKET] = tmp[1023];
    }
    __syncthreads();

    int chunk = (npts + NB - 1) / NB;     // SAME chunking as k_histA
    int begin = blk * chunk;
    int end   = begin + chunk; if (end > npts) end = npts;
    for (int i = begin + t; i < end; i += 1024) {
        float x0 = x[3 * i], x1 = x[3 * i + 1], x2 = x[3 * i + 2];
        int b = bucket_of(x0, x1, x2);
        unsigned pos = atomicAdd(&cur[b], 1u);   // LDS atomic
        perm[pos] = (unsigned)i;                 // 4B into 4MB — L2-friendly
    }
}

// ---- aux 3: coalesced sorted-payload build ----
// perm read sequential, x gather random (12MB -> L2-hit), xs write sequential.
__global__ __launch_bounds__(256)
void k_gather(const float* __restrict__ x, const unsigned* __restrict__ perm,
              float4* __restrict__ xs, int npts)
{
    int i = blockIdx.x * 256 + threadIdx.x;
    if (i >= npts) return;
    unsigned p = perm[i];
    float4 v;
    v.x = x[3 * p]; v.y = x[3 * p + 1]; v.z = x[3 * p + 2];
    v.w = __uint_as_float(p);
    xs[i] = v;
}

// ---- main: per-cell LDS corner cache, single pass over all 16 levels ----
// Box per level for cell i: lo=floor((i/16)*r), hi=ceil(((i+1)/16)*r).
// i*r<=2048 is fp32-exact, /16 dyadic-exact => bounds exact; fp-mul
// monotonicity => every per-point floor/ceil coord lies in [lo,hi].
// (R7/R9 form, verbatim: 107us, VALUBusy 78%, 4.5M bank conflicts.)

template<int MODE>   // 0: sorted xs.  1: perm + scattered x
__global__ __launch_bounds__(512, 8)
void k_main(const float4* __restrict__ xs, const float* __restrict__ x,
            const unsigned* __restrict__ perm,
            const unsigned* __restrict__ starts, const float2* __restrict__ tab,
            float4* __restrict__ out4)
{
    __shared__ float2 cache[CACHE_N];
    __shared__ int4 metaA[16];   // lo0, lo1, lo2, cbase
    __shared__ int4 metaB[16];   // n12, n2, bitcast(r), 0

    int cell = blockIdx.x;
    int startp = starts[cell], endp = starts[cell + 1];
    if (startp == endp) return;

    int ci = (cell >> 8) & 15, cj = (cell >> 4) & 15, ck = cell & 15;
    float fi0 = ci * 0.0625f, fi1 = (ci + 1) * 0.0625f;
    float fj0 = cj * 0.0625f, fj1 = (cj + 1) * 0.0625f;
    float fk0 = ck * 0.0625f, fk1 = (ck + 1) * 0.0625f;

    // -------- loader: all 512 threads, each unique corner gathered once ----
    int cbase = 0;
    #pragma unroll 1
    for (int l = 0; l < 16; ++l) {
        float r = c_res[l];
        int lo0 = (int)floorf(fi0 * r), hi0 = (int)ceilf(fi1 * r);
        int lo1 = (int)floorf(fj0 * r), hi1 = (int)ceilf(fj1 * r);
        int lo2 = (int)floorf(fk0 * r), hi2 = (int)ceilf(fk1 * r);
        int n0 = hi0 - lo0 + 1, n1 = hi1 - lo1 + 1, n2 = hi2 - lo2 + 1;
        int n12 = n1 * n2, tot = n0 * n12;
        for (int t = threadIdx.x; t < tot; t += 512) {
            int a = t / n12, rem = t - a * n12;
            int b = rem / n2, d = rem - b * n2;
            unsigned h = ((unsigned)(lo0 + a)
                        ^ ((unsigned)(lo1 + b) * PRIME1)
                        ^ ((unsigned)(lo2 + d) * PRIME2)) & TMASK;
            cache[cbase + t] = tab[h];
        }
        if (threadIdx.x == 0) {
            metaA[l] = make_int4(lo0, lo1, lo2, cbase);
            metaB[l] = make_int4(n12, n2, __float_as_int(r), 0);
        }
        cbase += tot;
    }
    __syncthreads();

    // -------- interp: all table reads from LDS, meta from LDS (uniform) ----
    auto lvl = [&](int l, float a0, float a1, float a2, float& ex, float& ey) {
        int4 mA = metaA[l];
        int4 mB = metaB[l];
        float r = __int_as_float(mB.z);
        int n12 = mB.x, n2 = mB.y;
        float s0 = a0 * r, s1 = a1 * r, s2 = a2 * r;   // lone mul == numpy
        float f0 = floorf(s0), f1 = floorf(s1), f2 = floorf(s2);
        float d0 = s0 - f0, d1 = s1 - f1, d2 = s2 - f2;
        int A0 = (int)f0 - mA.x, A1 = (int)f1 - mA.y, A2 = (int)f2 - mA.z;
        // ceil(s) = floor(s) + (s != floor(s)) for s >= 0
        int e0 = (d0 != 0.f) ? n12 : 0;
        int e1 = (d1 != 0.f) ? n2  : 0;
        int e2 = (d2 != 0.f) ? 1   : 0;
        int rA = mA.w + A0 * n12 + A1 * n2 + A2;

        float2 v0 = cache[rA];                 // 000
        float2 v1 = cache[rA + e0];            // 100
        float2 v2 = cache[rA + e1];            // 010
        float2 v3 = cache[rA + e2];            // 001
        float2 v4 = cache[rA + e0 + e1];       // 110
        float2 v5 = cache[rA + e0 + e2];       // 101
        float2 v6 = cache[rA + e1 + e2];       // 011
        float2 v7 = cache[rA + e0 + e1 + e2];  // 111

        float u0 = 1.f - d0, u1 = 1.f - d1, u2 = 1.f - d2;
        float pa = u1 * u2, pb = d1 * u2, pc = u1 * d2, pe = d1 * d2;
        float w0 = u0 * pa, w1 = d0 * pa, w2 = u0 * pb, w3 = u0 * pc;
        float w4 = d0 * pb, w5 = d0 * pc, w6 = u0 * pe, w7 = d0 * pe;

        float rx = v0.x * w0, ry = v0.y * w0;
        rx += v1.x * w1;  ry += v1.y * w1;
        rx += v2.x * w2;  ry += v2.y * w2;
        rx += v3.x * w3;  ry += v3.y * w3;
        rx += v4.x * w4;  ry += v4.y * w4;
        rx += v5.x * w5;  ry += v5.y * w5;
        rx += v6.x * w6;  ry += v6.y * w6;
        rx += v7.x * w7;  ry += v7.y * w7;
        ex = rx; ey = ry;
    };

    for (int sp = startp + (int)threadIdx.x; sp < endp; sp += 512) {
        float x0, x1, x2; unsigned p;
        if constexpr (MODE == 0) {
            float4 v = xs[sp];
            x0 = v.x; x1 = v.y; x2 = v.z; p = __float_as_uint(v.w);
        } else {
            p = perm[sp];
            x0 = x[3 * p]; x1 = x[3 * p + 1]; x2 = x[3 * p + 2];
        }
        // one thread writes the point's whole 128B output row, contiguously
        #pragma unroll 1
        for (int lp = 0; lp < 8; ++lp) {
            float4 o;
            lvl(2 * lp,     x0, x1, x2, o.x, o.y);
            lvl(2 * lp + 1, x0, x1, x2, o.z, o.w);
            out4[(size_t)p * 8 + lp] = o;
        }
    }
}

// Fallback (R1) if ws too small.
__global__ __launch_bounds__(256, 8)
void k_fallback(const float* __restrict__ x, const float2* __restrict__ tab,
                float2* __restrict__ out, int total) {
    int tid = blockIdx.x * 256 + threadIdx.x;
    if (tid >= total) return;
    int p = tid >> 4, l = tid & 15;
    float r = c_res[l];
    float s0 = x[3*p] * r, s1 = x[3*p+1] * r, s2 = x[3*p+2] * r;
    float f0 = floorf(s0), f1 = floorf(s1), f2 = floorf(s2);
    float d0 = s0 - f0, d1 = s1 - f1, d2 = s2 - f2;
    unsigned A0 = (unsigned)(int)f0, B0 = (unsigned)(int)ceilf(s0);
    unsigned A1 = (unsigned)(int)f1 * PRIME1, B1 = (unsigned)(int)ceilf(s1) * PRIME1;
    unsigned A2 = (unsigned)(int)f2 * PRIME2, B2 = (unsigned)(int)ceilf(s2) * PRIME2;
    unsigned h0=(A0^A1^A2)&TMASK, h1=(B0^A1^A2)&TMASK, h2=(A0^B1^A2)&TMASK;
    unsigned h3=(A0^A1^B2)&TMASK, h4=(B0^B1^A2)&TMASK, h5=(B0^A1^B2)&TMASK;
    unsigned h6=(A0^B1^B2)&TMASK, h7=(B0^B1^B2)&TMASK;
    float2 v0=tab[h0],v1=tab[h1],v2=tab[h2],v3=tab[h3];
    float2 v4=tab[h4],v5=tab[h5],v6=tab[h6],v7=tab[h7];
    float u0=1.f-d0,u1=1.f-d1,u2=1.f-d2;
    float ex = v0.x*(u0*u1*u2), ey = v0.y*(u0*u1*u2);
    ex += v1.x*(d0*u1*u2); ey += v1.y*(d0*u1*u2);
    ex += v2.x*(u0*d1*u2); ey += v2.y*(u0*d1*u2);
    ex += v3.x*(u0*u1*d2); ey += v3.y*(u0*u1*d2);
    ex += v4.x*(d0*d1*u2); ey += v4.y*(d0*d1*u2);
    ex += v5.x*(d0*u1*d2); ey += v5.y*(d0*u1*d2);
    ex += v6.x*(u0*d1*d2); ey += v6.y*(u0*d1*d2);
    ex += v7.x*(d0*d1*d2); ey += v7.y*(d0*d1*d2);
    float2 o; o.x = ex; o.y = ey; out[tid] = o;
}

extern "C" void kernel_launch(void* const* d_in, const int* in_sizes, int n_in,
                              void* d_out, int out_size, void* d_ws, size_t ws_size,
                              hipStream_t stream)
{
    const float*  x   = (const float*)d_in[0];
    const float2* tab = (const float2*)d_in[1];
    int npts = in_sizes[0] / 3;

    // ws layout (shared head)
    size_t off_grpsum = 0;                                        // 256 KB
    size_t off_cnt    = off_grpsum + (size_t)NGRP * NBUCKET * 4;  // 4 MB
    size_t off_starts = off_cnt    + (size_t)NB * NBUCKET * 4;
    size_t off_perm   = (off_starts + (size_t)(NBUCKET + 1) * 4 + 63)
                        & ~(size_t)63;
    size_t off_xs     = (off_perm + (size_t)npts * 4 + 63) & ~(size_t)63;

    // ---- Tier A: perm scatter + coalesced gather -> sorted xs (~24.3 MB) ----
    {
        size_t need = off_xs + (size_t)npts * 16;
        if (ws_size >= need) {
            unsigned* grpsum = (unsigned*)((char*)d_ws + off_grpsum);
            unsigned* cnt    = (unsigned*)((char*)d_ws + off_cnt);
            unsigned* starts = (unsigned*)((char*)d_ws + off_starts);
            unsigned* perm   = (unsigned*)((char*)d_ws + off_perm);
            float4*   xs     = (float4*)  ((char*)d_ws + off_xs);

            hipMemsetAsync(grpsum, 0, (size_t)NGRP * NBUCKET * 4, stream);
            k_histA   <<<NB, 1024, 0, stream>>>(x, cnt, grpsum, npts);
            k_scatB   <<<NB, 1024, 0, stream>>>(x, cnt, grpsum, starts,
                                                perm, npts);
            k_gather  <<<(npts + 255) / 256, 256, 0, stream>>>(x, perm,
                                                               xs, npts);
            k_main<0> <<<NBUCKET, 512, 0, stream>>>(xs, x, nullptr, starts,
                                                    tab, (float4*)d_out);
            return;
        }
    }

    // ---- Tier B: perm-only payload (~8.3 MB ws) ----
    {
        size_t need = off_perm + (size_t)npts * 4;
        if (ws_size >= need) {
            unsigned* grpsum = (unsigned*)((char*)d_ws + off_grpsum);
            unsigned* cnt    = (unsigned*)((char*)d_ws + off_cnt);
            unsigned* starts = (unsigned*)((char*)d_ws + off_starts);
            unsigned* perm   = (unsigned*)((char*)d_ws + off_perm);

            hipMemsetAsync(grpsum, 0, (size_t)NGRP * NBUCKET * 4, stream);
            k_histA   <<<NB, 1024, 0, stream>>>(x, cnt, grpsum, npts);
            k_scatB   <<<NB, 1024, 0, stream>>>(x, cnt, grpsum, starts,
                                                perm, npts);
            k_main<1> <<<NBUCKET, 512, 0, stream>>>(nullptr, x, perm, starts,
                                                    tab, (float4*)d_out);
            return;
        }
    }

    // ---- fallback ----
    int total = npts * 16;
    k_fallback<<<(total + 255) / 256, 256, 0, stream>>>(
        x, tab, (float2*)d_out, total);
}

// Round 7
// 242.150 us; speedup vs baseline: 1.0885x; 1.0885x over previous
//
#include <hip/hip_runtime.h>

// Instant-NGP multires hash encoding fwd. N=1M, L=16, F=2, T=2^19.
// R11 (from R10 @ 263.6us; best R9 @ 247.6us; k_main stable at 107us):
//  - Aux pinned at ~140us across 4 structural variants (R5/R8/R9/R10) while
//    its traffic is worth ~30us -> eliminate the prefix machinery entirely.
//  - Fixed-capacity buckets: xs[cell*CAP + slot]. ONE scatter kernel:
//    LDS hist -> per-(block,bucket) global range reservation (~660K atomics)
//    -> scatter. No colscan, no scan, no starts. k_main uses implicit
//    starts (cell*CAP) + cnt[cell], hot loop byte-identical to R9.
//  - Overflow (cnt>CAP; ~0 for uniform input at CAP>=280 ~ 2.3x mean) goes
//    to a list; k_main tail grid-strides it with direct tab gathers.

__constant__ float c_res[16] = {
    16.f, 18.f, 21.f, 24.f, 27.f, 32.f, 36.f, 42.f,
    48.f, 55.f, 64.f, 73.f, 84.f, 97.f, 111.f, 128.f
};

#define TMASK   0x7FFFFu
#define PRIME1  2654435761u
#define PRIME2  805459861u
#define NBUCKET 4096          // 16^3 cells
#define NB      256           // scatter blocks
#define NGRP    16            // (Tier B only)
#define CACHE_N 4467          // sum over levels of max corners — exact bound

__device__ __forceinline__ int bucket_of(float x0, float x1, float x2) {
    // x*16 is EXACT in fp32 (power-of-2 scale), so cell membership is exact.
    int c0 = (int)(x0 * 16.f); c0 = c0 < 0 ? 0 : (c0 > 15 ? 15 : c0);
    int c1 = (int)(x1 * 16.f); c1 = c1 < 0 ? 0 : (c1 > 15 ? 15 : c1);
    int c2 = (int)(x2 * 16.f); c2 = c2 < 0 ? 0 : (c2 > 15 ? 15 : c2);
    return (c0 << 8) | (c1 << 4) | c2;
}

// ---- one-kernel bucket scatter with fixed capacity ----
// Pass A: LDS hist of this block's chunk.  Pass B: reserve global ranges
// (h[j] becomes this block's global cursor for bucket j).  Pass C: re-read
// x (L2-hot), scatter to xs[b*cap + slot]; slot>=cap -> overflow list.
__global__ __launch_bounds__(1024)
void k_scat1(const float* __restrict__ x, unsigned* __restrict__ cnt,
             unsigned* __restrict__ ovfcnt, unsigned* __restrict__ ovfl,
             float4* __restrict__ xs, int npts, int cap, int ovfl_cap)
{
    __shared__ unsigned h[NBUCKET];
    for (int j = threadIdx.x; j < NBUCKET; j += 1024) h[j] = 0u;
    __syncthreads();
    int chunk = (npts + NB - 1) / NB;
    int begin = blockIdx.x * chunk;
    int end   = begin + chunk; if (end > npts) end = npts;

    for (int i = begin + threadIdx.x; i < end; i += 1024) {
        int b = bucket_of(x[3*i], x[3*i+1], x[3*i+2]);
        atomicAdd(&h[b], 1u);                    // LDS atomic
    }
    __syncthreads();
    for (int j = threadIdx.x; j < NBUCKET; j += 1024) {
        unsigned v = h[j];
        if (v) h[j] = atomicAdd(&cnt[j], v);     // reserve [base, base+v)
    }
    __syncthreads();
    for (int i = begin + threadIdx.x; i < end; i += 1024) {
        float x0 = x[3*i], x1 = x[3*i+1], x2 = x[3*i+2];   // L2-hot re-read
        int b = bucket_of(x0, x1, x2);
        unsigned slot = atomicAdd(&h[b], 1u);    // LDS atomic, global slot
        if (slot < (unsigned)cap) {
            float4 v; v.x = x0; v.y = x1; v.z = x2;
            v.w = __uint_as_float((unsigned)i);
            xs[(size_t)b * cap + slot] = v;
        } else {
            unsigned o = atomicAdd(ovfcnt, 1u);
            if (o < (unsigned)ovfl_cap) ovfl[o] = (unsigned)i;
        }
    }
}

// ---- Tier B aux (R9 path, proven): hist + prefix-rebuild scatter ----
__global__ __launch_bounds__(1024)
void k_histA(const float* __restrict__ x, unsigned* __restrict__ cnt,
             unsigned* __restrict__ grpsum, int npts)
{
    __shared__ unsigned h[NBUCKET];
    for (int j = threadIdx.x; j < NBUCKET; j += 1024) h[j] = 0u;
    __syncthreads();
    int chunk = (npts + NB - 1) / NB;
    int begin = blockIdx.x * chunk;
    int end   = begin + chunk; if (end > npts) end = npts;
    for (int i = begin + threadIdx.x; i < end; i += 1024) {
        int b = bucket_of(x[3 * i], x[3 * i + 1], x[3 * i + 2]);
        atomicAdd(&h[b], 1u);
    }
    __syncthreads();
    unsigned* grow = grpsum + (size_t)(blockIdx.x >> 4) * NBUCKET;
    for (int j = threadIdx.x; j < NBUCKET; j += 1024) {
        unsigned v = h[j];
        cnt[(size_t)blockIdx.x * NBUCKET + j] = v;
        if (v) atomicAdd(&grow[j], v);
    }
}

__global__ __launch_bounds__(1024)
void k_scatB(const float* __restrict__ x, const unsigned* __restrict__ cnt,
             const unsigned* __restrict__ grpsum, unsigned* __restrict__ starts,
             unsigned* __restrict__ perm, int npts)
{
    __shared__ unsigned cur[NBUCKET];
    __shared__ unsigned tmp[1024];
    const int t   = threadIdx.x;
    const int blk = blockIdx.x;
    const int myg = blk >> 4;
    const int r0  = blk & ~15;

    const uint4* gs4 = (const uint4*)grpsum;
    const uint4* ct4 = (const uint4*)cnt;
    uint4 tot = make_uint4(0u,0u,0u,0u), bas = make_uint4(0u,0u,0u,0u);
    #pragma unroll
    for (int g = 0; g < NGRP; ++g) {
        uint4 v = gs4[g * 1024 + t];
        tot.x += v.x; tot.y += v.y; tot.z += v.z; tot.w += v.w;
        if (g < myg) { bas.x += v.x; bas.y += v.y; bas.z += v.z; bas.w += v.w; }
    }
    for (int r = r0; r < blk; ++r) {
        uint4 v = ct4[r * 1024 + t];
        bas.x += v.x; bas.y += v.y; bas.z += v.z; bas.w += v.w;
    }
    unsigned s = tot.x + tot.y + tot.z + tot.w;
    tmp[t] = s;
    __syncthreads();
    for (int off = 1; off < 1024; off <<= 1) {
        unsigned u = (t >= off) ? tmp[t - off] : 0u;
        __syncthreads();
        tmp[t] += u;
        __syncthreads();
    }
    unsigned excl = tmp[t] - s;
    unsigned s0 = excl, s1 = s0 + tot.x, s2 = s1 + tot.y, s3 = s2 + tot.z;
    cur[4*t+0] = s0 + bas.x;
    cur[4*t+1] = s1 + bas.y;
    cur[4*t+2] = s2 + bas.z;
    cur[4*t+3] = s3 + bas.w;
    if (blk == 0) {
        starts[4*t+0] = s0; starts[4*t+1] = s1;
        starts[4*t+2] = s2; starts[4*t+3] = s3;
        if (t == 1023) starts[NBUCKET] = tmp[1023];
    }
    __syncthreads();

    int chunk = (npts + NB - 1) / NB;
    int begin = blk * chunk;
    int end   = begin + chunk; if (end > npts) end = npts;
    for (int i = begin + t; i < end; i += 1024) {
        float x0 = x[3 * i], x1 = x[3 * i + 1], x2 = x[3 * i + 2];
        int b = bucket_of(x0, x1, x2);
        unsigned pos = atomicAdd(&cur[b], 1u);
        perm[pos] = (unsigned)i;
    }
}

// ---- per-point direct evaluation (overflow tail / fallback math) ----
__device__ __forceinline__ void point_direct(const float* __restrict__ x,
                                             const float2* __restrict__ tab,
                                             float4* __restrict__ out4,
                                             unsigned p)
{
    float a0 = x[3*p], a1 = x[3*p+1], a2 = x[3*p+2];
    #pragma unroll 1
    for (int lp = 0; lp < 8; ++lp) {
        float4 o;
        #pragma unroll
        for (int half = 0; half < 2; ++half) {
            int l = 2 * lp + half;
            float r = c_res[l];
            float s0 = a0 * r, s1 = a1 * r, s2 = a2 * r;
            float f0 = floorf(s0), f1 = floorf(s1), f2 = floorf(s2);
            float d0 = s0 - f0, d1 = s1 - f1, d2 = s2 - f2;
            unsigned A0 = (unsigned)(int)f0, B0 = (unsigned)(int)ceilf(s0);
            unsigned A1 = (unsigned)(int)f1 * PRIME1,
                     B1 = (unsigned)(int)ceilf(s1) * PRIME1;
            unsigned A2 = (unsigned)(int)f2 * PRIME2,
                     B2 = (unsigned)(int)ceilf(s2) * PRIME2;
            float2 v0 = tab[(A0^A1^A2)&TMASK], v1 = tab[(B0^A1^A2)&TMASK];
            float2 v2 = tab[(A0^B1^A2)&TMASK], v3 = tab[(A0^A1^B2)&TMASK];
            float2 v4 = tab[(B0^B1^A2)&TMASK], v5 = tab[(B0^A1^B2)&TMASK];
            float2 v6 = tab[(A0^B1^B2)&TMASK], v7 = tab[(B0^B1^B2)&TMASK];
            float u0 = 1.f-d0, u1 = 1.f-d1, u2 = 1.f-d2;
            float ex = v0.x*(u0*u1*u2), ey = v0.y*(u0*u1*u2);
            ex += v1.x*(d0*u1*u2); ey += v1.y*(d0*u1*u2);
            ex += v2.x*(u0*d1*u2); ey += v2.y*(u0*d1*u2);
            ex += v3.x*(u0*u1*d2); ey += v3.y*(u0*u1*d2);
            ex += v4.x*(d0*d1*u2); ey += v4.y*(d0*d1*u2);
            ex += v5.x*(d0*u1*d2); ey += v5.y*(d0*u1*d2);
            ex += v6.x*(u0*d1*d2); ey += v6.y*(u0*d1*d2);
            ex += v7.x*(d0*d1*d2); ey += v7.y*(d0*d1*d2);
            if (half) { o.z = ex; o.w = ey; } else { o.x = ex; o.y = ey; }
        }
        out4[(size_t)p * 8 + lp] = o;
    }
}

// ---- main: per-cell LDS corner cache, single pass over all 16 levels ----
// (R7/R9 hot loop verbatim: 107us, VALUBusy 78%, 4.5M bank conflicts.)

template<int MODE>   // 0: fixed-cap xs + cnt.  1: perm + scattered x + starts
__global__ __launch_bounds__(512, 8)
void k_main(const float4* __restrict__ xs, const float* __restrict__ x,
            const unsigned* __restrict__ perm,
            const unsigned* __restrict__ starts, const float2* __restrict__ tab,
            float4* __restrict__ out4, const unsigned* __restrict__ cnt,
            const unsigned* __restrict__ ovfcnt,
            const unsigned* __restrict__ ovfl, int cap, int ovfl_cap)
{
    __shared__ float2 cache[CACHE_N];
    __shared__ int4 metaA[16];   // lo0, lo1, lo2, cbase
    __shared__ int4 metaB[16];   // n12, n2, bitcast(r), 0

    int cell = blockIdx.x;
    int startp, endp;
    if constexpr (MODE == 0) {
        unsigned cn = cnt[cell];
        if (cn > (unsigned)cap) cn = (unsigned)cap;
        startp = cell * cap;
        endp   = startp + (int)cn;
    } else {
        startp = starts[cell]; endp = starts[cell + 1];
    }

    if (startp < endp) {
        int ci = (cell >> 8) & 15, cj = (cell >> 4) & 15, ck = cell & 15;
        float fi0 = ci * 0.0625f, fi1 = (ci + 1) * 0.0625f;
        float fj0 = cj * 0.0625f, fj1 = (cj + 1) * 0.0625f;
        float fk0 = ck * 0.0625f, fk1 = (ck + 1) * 0.0625f;

        // ---- loader: all 512 threads, each unique corner gathered once ----
        int cbase = 0;
        #pragma unroll 1
        for (int l = 0; l < 16; ++l) {
            float r = c_res[l];
            int lo0 = (int)floorf(fi0 * r), hi0 = (int)ceilf(fi1 * r);
            int lo1 = (int)floorf(fj0 * r), hi1 = (int)ceilf(fj1 * r);
            int lo2 = (int)floorf(fk0 * r), hi2 = (int)ceilf(fk1 * r);
            int n0 = hi0 - lo0 + 1, n1 = hi1 - lo1 + 1, n2 = hi2 - lo2 + 1;
            int n12 = n1 * n2, tot = n0 * n12;
            for (int t = threadIdx.x; t < tot; t += 512) {
                int a = t / n12, rem = t - a * n12;
                int b = rem / n2, d = rem - b * n2;
                unsigned hh = ((unsigned)(lo0 + a)
                            ^ ((unsigned)(lo1 + b) * PRIME1)
                            ^ ((unsigned)(lo2 + d) * PRIME2)) & TMASK;
                cache[cbase + t] = tab[hh];
            }
            if (threadIdx.x == 0) {
                metaA[l] = make_int4(lo0, lo1, lo2, cbase);
                metaB[l] = make_int4(n12, n2, __float_as_int(r), 0);
            }
            cbase += tot;
        }
        __syncthreads();

        auto lvl = [&](int l, float a0, float a1, float a2,
                       float& ex, float& ey) {
            int4 mA = metaA[l];
            int4 mB = metaB[l];
            float r = __int_as_float(mB.z);
            int n12 = mB.x, n2 = mB.y;
            float s0 = a0 * r, s1 = a1 * r, s2 = a2 * r;  // lone mul == numpy
            float f0 = floorf(s0), f1 = floorf(s1), f2 = floorf(s2);
            float d0 = s0 - f0, d1 = s1 - f1, d2 = s2 - f2;
            int A0 = (int)f0 - mA.x, A1 = (int)f1 - mA.y, A2 = (int)f2 - mA.z;
            int e0 = (d0 != 0.f) ? n12 : 0;
            int e1 = (d1 != 0.f) ? n2  : 0;
            int e2 = (d2 != 0.f) ? 1   : 0;
            int rA = mA.w + A0 * n12 + A1 * n2 + A2;

            float2 v0 = cache[rA];                 // 000
            float2 v1 = cache[rA + e0];            // 100
            float2 v2 = cache[rA + e1];            // 010
            float2 v3 = cache[rA + e2];            // 001
            float2 v4 = cache[rA + e0 + e1];       // 110
            float2 v5 = cache[rA + e0 + e2];       // 101
            float2 v6 = cache[rA + e1 + e2];       // 011
            float2 v7 = cache[rA + e0 + e1 + e2];  // 111

            float u0 = 1.f - d0, u1 = 1.f - d1, u2 = 1.f - d2;
            float pa = u1 * u2, pb = d1 * u2, pc = u1 * d2, pe = d1 * d2;
            float w0 = u0 * pa, w1 = d0 * pa, w2 = u0 * pb, w3 = u0 * pc;
            float w4 = d0 * pb, w5 = d0 * pc, w6 = u0 * pe, w7 = d0 * pe;

            float rx = v0.x * w0, ry = v0.y * w0;
            rx += v1.x * w1;  ry += v1.y * w1;
            rx += v2.x * w2;  ry += v2.y * w2;
            rx += v3.x * w3;  ry += v3.y * w3;
            rx += v4.x * w4;  ry += v4.y * w4;
            rx += v5.x * w5;  ry += v5.y * w5;
            rx += v6.x * w6;  ry += v6.y * w6;
            rx += v7.x * w7;  ry += v7.y * w7;
            ex = rx; ey = ry;
        };

        for (int sp = startp + (int)threadIdx.x; sp < endp; sp += 512) {
            float x0, x1, x2; unsigned p;
            if constexpr (MODE == 0) {
                float4 v = xs[sp];
                x0 = v.x; x1 = v.y; x2 = v.z; p = __float_as_uint(v.w);
            } else {
                p = perm[sp];
                x0 = x[3 * p]; x1 = x[3 * p + 1]; x2 = x[3 * p + 2];
            }
            // one thread writes the point's whole 128B row, contiguously
            #pragma unroll 1
            for (int lp = 0; lp < 8; ++lp) {
                float4 o;
                lvl(2 * lp,     x0, x1, x2, o.x, o.y);
                lvl(2 * lp + 1, x0, x1, x2, o.z, o.w);
                out4[(size_t)p * 8 + lp] = o;
            }
        }
    }

    // ---- overflow tail (MODE 0): ~zero cost when empty ----
    if constexpr (MODE == 0) {
        unsigned ovfn = *ovfcnt;
        if (ovfn > (unsigned)ovfl_cap) ovfn = (unsigned)ovfl_cap;
        for (unsigned u = blockIdx.x * 512u + threadIdx.x; u < ovfn;
             u += 4096u * 512u)
            point_direct(x, tab, out4, ovfl[u]);
    }
}

// Fallback (R1) if ws too small.
__global__ __launch_bounds__(256, 8)
void k_fallback(const float* __restrict__ x, const float2* __restrict__ tab,
                float2* __restrict__ out, int total) {
    int tid = blockIdx.x * 256 + threadIdx.x;
    if (tid >= total) return;
    int p = tid >> 4, l = tid & 15;
    float r = c_res[l];
    float s0 = x[3*p] * r, s1 = x[3*p+1] * r, s2 = x[3*p+2] * r;
    float f0 = floorf(s0), f1 = floorf(s1), f2 = floorf(s2);
    float d0 = s0 - f0, d1 = s1 - f1, d2 = s2 - f2;
    unsigned A0 = (unsigned)(int)f0, B0 = (unsigned)(int)ceilf(s0);
    unsigned A1 = (unsigned)(int)f1 * PRIME1, B1 = (unsigned)(int)ceilf(s1) * PRIME1;
    unsigned A2 = (unsigned)(int)f2 * PRIME2, B2 = (unsigned)(int)ceilf(s2) * PRIME2;
    unsigned h0=(A0^A1^A2)&TMASK, h1=(B0^A1^A2)&TMASK, h2=(A0^B1^A2)&TMASK;
    unsigned h3=(A0^A1^B2)&TMASK, h4=(B0^B1^A2)&TMASK, h5=(B0^A1^B2)&TMASK;
    unsigned h6=(A0^B1^B2)&TMASK, h7=(B0^B1^B2)&TMASK;
    float2 v0=tab[h0],v1=tab[h1],v2=tab[h2],v3=tab[h3];
    float2 v4=tab[h4],v5=tab[h5],v6=tab[h6],v7=tab[h7];
    float u0=1.f-d0,u1=1.f-d1,u2=1.f-d2;
    float ex = v0.x*(u0*u1*u2), ey = v0.y*(u0*u1*u2);
    ex += v1.x*(d0*u1*u2); ey += v1.y*(d0*u1*u2);
    ex += v2.x*(u0*d1*u2); ey += v2.y*(u0*d1*u2);
    ex += v3.x*(u0*u1*d2); ey += v3.y*(u0*u1*d2);
    ex += v4.x*(d0*d1*u2); ey += v4.y*(d0*d1*u2);
    ex += v5.x*(d0*u1*d2); ey += v5.y*(d0*u1*d2);
    ex += v6.x*(u0*d1*d2); ey += v6.y*(u0*d1*d2);
    ex += v7.x*(d0*d1*d2); ey += v7.y*(d0*d1*d2);
    float2 o; o.x = ex; o.y = ey; out[tid] = o;
}

extern "C" void kernel_launch(void* const* d_in, const int* in_sizes, int n_in,
                              void* d_out, int out_size, void* d_ws, size_t ws_size,
                              hipStream_t stream)
{
    const float*  x   = (const float*)d_in[0];
    const float2* tab = (const float2*)d_in[1];
    int npts = in_sizes[0] / 3;

    // ---- Tier A: fixed-capacity buckets, 1 aux kernel ----
    {
        size_t off_cnt  = 0;                                       // 16 KB
        size_t off_ovfc = off_cnt + (size_t)NBUCKET * 4;           // 64 B slot
        size_t off_ovfl = (off_ovfc + 64 + 63) & ~(size_t)63;      // npts*4
        size_t off_xs   = (off_ovfl + (size_t)npts * 4 + 255) & ~(size_t)255;
        if (ws_size > off_xs) {
            size_t avail = ws_size - off_xs;
            long long capll = (long long)(avail / ((size_t)NBUCKET * 16));
            int cap = (int)(capll > 512 ? 512 : capll);
            // need cap comfortably above mean npts/4096 (uniform input);
            // overflow handled correctly regardless, but keep it rare.
            int mean = npts / NBUCKET + 1;
            if (cap >= mean + (mean + 3) / 4 + 64) {
                unsigned* cnt    = (unsigned*)((char*)d_ws + off_cnt);
                unsigned* ovfc   = (unsigned*)((char*)d_ws + off_ovfc);
                unsigned* ovfl   = (unsigned*)((char*)d_ws + off_ovfl);
                float4*   xs     = (float4*)  ((char*)d_ws + off_xs);

                hipMemsetAsync((char*)d_ws + off_cnt, 0,
                               (size_t)NBUCKET * 4 + 64, stream);
                k_scat1 <<<NB, 1024, 0, stream>>>(x, cnt, ovfc, ovfl, xs,
                                                  npts, cap, npts);
                k_main<0><<<NBUCKET, 512, 0, stream>>>(xs, x, nullptr, nullptr,
                                                       tab, (float4*)d_out,
                                                       cnt, ovfc, ovfl,
                                                       cap, npts);
                return;
            }
        }
    }

    // ---- Tier B: perm-only path (R9, ~8.3 MB ws) ----
    {
        size_t off_grpsum = 0;                                        // 256 KB
        size_t off_cnt    = off_grpsum + (size_t)NGRP * NBUCKET * 4;  // 4 MB
        size_t off_starts = off_cnt    + (size_t)NB * NBUCKET * 4;
        size_t off_perm   = (off_starts + (size_t)(NBUCKET + 1) * 4 + 63)
                            & ~(size_t)63;
        size_t need       = off_perm + (size_t)npts * 4;
        if (ws_size >= need) {
            unsigned* grpsum = (unsigned*)((char*)d_ws + off_grpsum);
            unsigned* cnt    = (unsigned*)((char*)d_ws + off_cnt);
            unsigned* starts = (unsigned*)((char*)d_ws + off_starts);
            unsigned* perm   = (unsigned*)((char*)d_ws + off_perm);

            hipMemsetAsync(grpsum, 0, (size_t)NGRP * NBUCKET * 4, stream);
            k_histA   <<<NB, 1024, 0, stream>>>(x, cnt, grpsum, npts);
            k_scatB   <<<NB, 1024, 0, stream>>>(x, cnt, grpsum, starts,
                                                perm, npts);
            k_main<1> <<<NBUCKET, 512, 0, stream>>>(nullptr, x, perm, starts,
                                                    tab, (float4*)d_out,
                                                    nullptr, nullptr, nullptr,
                                                    0, 0);
            return;
        }
    }

    // ---- fallback ----
    int total = npts * 16;
    k_fallback<<<(total + 255) / 256, 256, 0, stream>>>(
        x, tab, (float2*)d_out, total);
}